// Round 12
// baseline (25858.975 us; speedup 1.0000x reference)
//
#include <hip/hip_runtime.h>
#include <math.h>

#define DINLINE __device__ __forceinline__

DINLINE float sigmoidf_(float x) { return 1.f / (1.f + expf(-x)); }

// All scratch in static device memory — independent of ws_size (graph-safe, R3-R11 verified).
__device__ __align__(256) float g_ws[36200000];

// ---- grid-wide tree barrier state (decoder only). Reset before each dec_persist launch. ----
__device__ unsigned g_cnt;                        // level-2 arrival (16 group-lasts)
__device__ unsigned g_epoch;                      // global release flag
__device__ __align__(128) unsigned g_arr[16 * 32];  // per-group arrival counters, 128B apart
__device__ __align__(128) unsigned g_sub[16 * 32];  // per-group release flags, 128B apart

// Two-level ARRIVAL (16 parallel lines x 16 serial RMWs; R11 was 256 serial on one line
// = ~64us/barrier) + two-level WAIT (R11-proven). Device-scope atomics = cross-XCD
// coherent point; spin via atomic RMW-read (never a cacheable load).
#define GRID_BAR()                                                          \
  do {                                                                      \
    __syncthreads();                                                        \
    if (threadIdx.x == 0) {                                                 \
      __threadfence();                                                      \
      bar_target += 1u;                                                     \
      int grp_ = blockIdx.x >> 4;                                           \
      unsigned p_ = atomicAdd(&g_arr[grp_ * 32], 1u);                       \
      if (p_ == 15u) {                                                      \
        atomicExch(&g_arr[grp_ * 32], 0u);                                  \
        unsigned q_ = atomicAdd(&g_cnt, 1u);                                \
        if (q_ == 15u) {                                                    \
          atomicExch(&g_cnt, 0u);                                           \
          __threadfence();                                                  \
          atomicExch(&g_epoch, bar_target);                                 \
        }                                                                   \
      }                                                                     \
      if ((blockIdx.x & 15) == 0) {                                         \
        while (atomicAdd(&g_epoch, 0u) < bar_target)                        \
          __builtin_amdgcn_s_sleep(8);                                      \
        atomicExch(&g_sub[grp_ * 32], bar_target);                          \
      } else {                                                              \
        while (atomicAdd(&g_sub[grp_ * 32], 0u) < bar_target)               \
          __builtin_amdgcn_s_sleep(8);                                      \
      }                                                                     \
      __threadfence();                                                      \
    }                                                                       \
    __syncthreads();                                                        \
  } while (0)

__global__ void reset_bar_kernel() {
  int i = threadIdx.x;
  if (i == 0) { g_cnt = 0u; g_epoch = 0u; }
  if (i < 16) { g_arr[i * 32] = 0u; g_sub[i * 32] = 0u; }
}

// ---------------- im2col for the two convs ----------------
__global__ void im2col1_kernel(const float* __restrict__ feat, float* __restrict__ P) {
  size_t i = (size_t)blockIdx.x * 256 + threadIdx.x;
  int col = (int)(i % 1280);
  int row = (int)(i / 1280);
  int c = col / 5, k = col - c * 5;
  int l = row & 255, b = row >> 8;
  int pos = 2 * l + k - 2;
  P[i] = (pos >= 0 && pos < 512) ? feat[((size_t)b * 512 + pos) * 256 + c] : 0.f;
}

__global__ void im2col2_kernel(const float* __restrict__ y1, float* __restrict__ P) {
  size_t i = (size_t)blockIdx.x * 256 + threadIdx.x;
  int col = (int)(i % 2560);
  int row = (int)(i / 2560);
  int c = col / 5, k = col - c * 5;
  int l = row & 127, b = row >> 7;
  int pos = 2 * l + k - 2;
  P[i] = (pos >= 0 && pos < 256) ? y1[((size_t)b * 256 + pos) * 512 + c] : 0.f;
}

// ---------------- fp32 tiled GEMM (R4-verified) ----------------
__global__ __launch_bounds__(256) void sgemm128(
    const float* __restrict__ A, const float* __restrict__ B,
    const float* __restrict__ bias, float* __restrict__ C,
    int M, int N, int K, int relu) {
  __shared__ float As[8][132];
  __shared__ float Bs[8][132];
  int bm = blockIdx.y * 128, bn = blockIdx.x * 128;
  int tid = threadIdx.x;
  int tx = tid & 15, ty = tid >> 4;
  float acc[8][8];
#pragma unroll
  for (int i = 0; i < 8; ++i)
#pragma unroll
    for (int j = 0; j < 8; ++j) acc[i][j] = 0.f;
  int lr = tid >> 1;
  int lc = (tid & 1) * 4;
  const float* Arow = A + (size_t)(bm + lr) * K + lc;
  const float* Brow = B + (size_t)(bn + lr) * K + lc;
  for (int k0 = 0; k0 < K; k0 += 8) {
    float4 av = *(const float4*)(Arow + k0);
    float4 bv = *(const float4*)(Brow + k0);
    As[lc + 0][lr] = av.x; As[lc + 1][lr] = av.y; As[lc + 2][lr] = av.z; As[lc + 3][lr] = av.w;
    Bs[lc + 0][lr] = bv.x; Bs[lc + 1][lr] = bv.y; Bs[lc + 2][lr] = bv.z; Bs[lc + 3][lr] = bv.w;
    __syncthreads();
#pragma unroll
    for (int kk = 0; kk < 8; ++kk) {
      float4 a0 = *(const float4*)&As[kk][ty * 8];
      float4 a1 = *(const float4*)&As[kk][ty * 8 + 4];
      float4 b0 = *(const float4*)&Bs[kk][tx * 8];
      float4 b1 = *(const float4*)&Bs[kk][tx * 8 + 4];
      float aa[8] = {a0.x, a0.y, a0.z, a0.w, a1.x, a1.y, a1.z, a1.w};
      float bb[8] = {b0.x, b0.y, b0.z, b0.w, b1.x, b1.y, b1.z, b1.w};
#pragma unroll
      for (int i = 0; i < 8; ++i)
#pragma unroll
        for (int j = 0; j < 8; ++j) acc[i][j] += aa[i] * bb[j];
    }
    __syncthreads();
  }
#pragma unroll
  for (int i = 0; i < 8; ++i) {
    int m = bm + ty * 8 + i;
#pragma unroll
    for (int j = 0; j < 8; ++j) {
      int n = bn + tx * 8 + j;
      float v = acc[i][j] + (bias ? bias[n] : 0.f);
      if (relu) v = fmaxf(v, 0.f);
      C[(size_t)m * N + n] = v;
    }
  }
}

// ---------------- persistent per-(dir,b) encoder (R11-verified) ----------------
__global__ __launch_bounds__(1024) void enc_persist2(
    const float* __restrict__ gi_f, const float* __restrict__ gi_b,
    const float* __restrict__ Whh_f, const float* __restrict__ bhh_f,
    const float* __restrict__ Whh_b, const float* __restrict__ bhh_b,
    float* __restrict__ h_fin, float* __restrict__ enc_out) {
  __shared__ float hcur[512];
  __shared__ float gh[1536];
  int swz = blockIdx.x & 7;
  int dir = swz >> 2;
  int b = ((blockIdx.x >> 3) << 2) | (swz & 3);
  int tid = threadIdx.x;
  int sl = tid & 7, nl = tid >> 3;
  const float* gi  = dir ? gi_b  : gi_f;
  const float* Whh = dir ? Whh_b : Whh_f;
  const float* bhh = dir ? bhh_b : bhh_f;
  float bhr = 0.f, bhz = 0.f, bhn = 0.f;
  if (tid < 512) {
    hcur[tid] = 0.f;
    bhr = bhh[tid]; bhz = bhh[512 + tid]; bhn = bhh[1024 + tid];
  }
  __syncthreads();
  for (int s = 0; s < 128; ++s) {
    int t = dir ? (127 - s) : s;
#pragma unroll 2
    for (int pass = 0; pass < 12; ++pass) {
      int m = pass * 128 + nl;
      const float4* wp = (const float4*)(Whh + (size_t)m * 512);
      float a = 0.f;
#pragma unroll
      for (int q = 0; q < 16; ++q) {
        float4 wv = wp[q * 8 + sl];
        float4 hv = *(const float4*)&hcur[(q * 8 + sl) * 4];
        a += wv.x * hv.x + wv.y * hv.y + wv.z * hv.z + wv.w * hv.w;
      }
      a += __shfl_xor(a, 1);
      a += __shfl_xor(a, 2);
      a += __shfl_xor(a, 4);
      if (sl == 0) gh[m] = a;
    }
    __syncthreads();
    if (tid < 512) {
      int j = tid;
      const float* g = gi + ((size_t)b * 128 + t) * 1536;
      float r = sigmoidf_(g[j] + gh[j] + bhr);
      float z = sigmoidf_(g[512 + j] + gh[512 + j] + bhz);
      float n = tanhf(g[1024 + j] + r * (gh[1024 + j] + bhn));
      float hnew = (1.f - z) * n + z * hcur[j];
      hcur[j] = hnew;
      enc_out[((size_t)b * 128 + t) * 1024 + dir * 512 + j] = hnew;
    }
    __syncthreads();
  }
  if (tid < 512) h_fin[dir * 16384 + b * 512 + tid] = hcur[tid];
}

// ---------------- batch-shared GEMV (bridge only; R5-verified) ----------------
__global__ __launch_bounds__(256) void gemvB(
    const float* __restrict__ A1, const int* __restrict__ tokidx, int len1,
    const float* __restrict__ A2, int len2,
    const float* __restrict__ W, const float* __restrict__ bias,
    float* __restrict__ out0, float* __restrict__ out1, int split, int N, int K) {
  int tid = threadIdx.x;
  int s = tid & 7, nl = tid >> 3;
  int n = blockIdx.x * 32 + nl;
  __shared__ float4 xs4[32 * 32];
  float acc[32];
#pragma unroll
  for (int b = 0; b < 32; ++b) acc[b] = 0.f;
  const float4* W4 = (const float4*)(W + (size_t)n * K);
  int K4 = K >> 2;
  int len1_4 = len1 >> 2;
  for (int k0 = 0; k0 < K4; k0 += 32) {
    __syncthreads();
    for (int idx = tid; idx < 1024; idx += 256) {
      int b = idx >> 5, kf = idx & 31;
      int gk = k0 + kf;
      float4 v;
      if (gk < len1_4) {
        const float* src = tokidx ? (A1 + (size_t)tokidx[b] * len1) : (A1 + (size_t)b * len1);
        v = ((const float4*)src)[gk];
      } else {
        v = ((const float4*)(A2 + (size_t)b * len2))[gk - len1_4];
      }
      xs4[idx] = v;
    }
    __syncthreads();
    const float4* wp = W4 + k0;
#pragma unroll
    for (int j = 0; j < 4; ++j) {
      float4 wv = wp[j * 8 + s];
      const float4* xp = xs4 + j * 8 + s;
#pragma unroll
      for (int b = 0; b < 32; ++b) {
        float4 xv = xp[b * 32];
        acc[b] += wv.x * xv.x + wv.y * xv.y + wv.z * xv.z + wv.w * xv.w;
      }
    }
  }
#pragma unroll
  for (int b = 0; b < 32; ++b) {
    float v = acc[b];
    v += __shfl_xor(v, 1);
    v += __shfl_xor(v, 2);
    v += __shfl_xor(v, 4);
    acc[b] = v;
  }
  if (s == 0) {
    float bv = bias ? bias[n] : 0.f;
#pragma unroll
    for (int b = 0; b < 32; ++b) {
      float val = acc[b] + bv;
      if (n < split) out0[(size_t)b * split + n] = val;
      else out1[(size_t)b * (N - split) + (n - split)] = val;
    }
  }
}

// ---------------- persistent decoder: 49 steps x 4 phases ----------------
// LDS: SB 48KB (proj x-stage [32][96]f4; GRU chunks use stride-32 region) + ksh 8.4KB
// + d/hb/red/sc ≈ 62KB total. 1 block/CU.
__global__ __launch_bounds__(256) void dec_persist(
    const float* __restrict__ emb, const float* __restrict__ attn_Wd,
    const float* __restrict__ attn_v,
    const float* __restrict__ enc_pj, const float* __restrict__ enc_out,
    const float* __restrict__ dec_Wih0, const float* __restrict__ dec_bih0,
    const float* __restrict__ dec_Whh0, const float* __restrict__ dec_bhh0,
    const float* __restrict__ dec_Wih1, const float* __restrict__ dec_bih1,
    const float* __restrict__ dec_Whh1, const float* __restrict__ dec_bhh1,
    const float* __restrict__ proj_W, const float* __restrict__ proj_b,
    float* __restrict__ h0d, float* __restrict__ h1d,
    float* __restrict__ ctxb,
    unsigned long long* __restrict__ keys, int* __restrict__ tok,
    int* __restrict__ decoded) {
  __shared__ float4 SB[3072];                    // 48KB
  __shared__ unsigned long long ksh[32 * 33];    // 8.4KB
  __shared__ float d_s[512];
  __shared__ float hb_s[512];
  __shared__ float red_s[256];
  __shared__ float sc_s[128];
  unsigned bar_target = 0u;
  int blk = blockIdx.x, tid = threadIdx.x;
  int s8 = tid & 7, nl = tid >> 3;               // gemv roles
  int bb31 = tid & 31, jj = tid >> 5;            // gru roles

  for (int s = 0; s < 49; ++s) {
    int cur = s & 1, nxt = (s + 1) & 1;
    const float* h1cur = h1d + cur * 16384;

    // ---- phase A: full attention per-b (dW inline from L2) ; blk32 decode+zero keys ----
    if (blk < 32) {
      int b = blk;
      hb_s[tid] = h1cur[b * 512 + tid];
      hb_s[tid + 256] = h1cur[b * 512 + 256 + tid];
      __syncthreads();
      // d[a] = Wd[a,:] . h1[b,:]  — 16 passes x 32 rows x 8 slices, shfl reduce
      for (int pass = 0; pass < 16; ++pass) {
        int a = pass * 32 + nl;
        const float4* wp = (const float4*)(attn_Wd + (size_t)a * 512);
        float sum = 0.f;
#pragma unroll
        for (int q = 0; q < 16; ++q) {
          float4 wv = wp[q * 8 + s8];
          float4 hv = *(const float4*)&hb_s[(q * 8 + s8) * 4];
          sum += wv.x * hv.x + wv.y * hv.y + wv.z * hv.z + wv.w * hv.w;
        }
        sum += __shfl_xor(sum, 1);
        sum += __shfl_xor(sum, 2);
        sum += __shfl_xor(sum, 4);
        if (s8 == 0) d_s[a] = sum;
      }
      __syncthreads();
      {
        int t = tid >> 1, part = tid & 1;
        const float* ep = enc_pj + ((size_t)b * 128 + t) * 512 + part * 256;
        const float* dd = d_s + part * 256;
        const float* vv = attn_v + part * 256;
        float sv = 0.f;
        for (int a = 0; a < 256; ++a) sv += tanhf(ep[a] + dd[a]) * vv[a];
        red_s[tid] = sv;
      }
      __syncthreads();
      if (tid < 128) sc_s[tid] = red_s[tid * 2] + red_s[tid * 2 + 1];
      __syncthreads();
      if (tid == 0) {
        float m = -1e30f;
        for (int t = 0; t < 128; ++t) m = fmaxf(m, sc_s[t]);
        float sum = 0.f;
        for (int t = 0; t < 128; ++t) { float e = expf(sc_s[t] - m); sc_s[t] = e; sum += e; }
        float inv = 1.f / sum;
        for (int t = 0; t < 128; ++t) sc_s[t] *= inv;
      }
      __syncthreads();
      for (int e = tid; e < 1024; e += 256) {
        const float* eo = enc_out + (size_t)b * 131072 + e;
        float sv = 0.f;
        for (int t = 0; t < 128; ++t) sv += sc_s[t] * eo[(size_t)t * 1024];
        ctxb[b * 1024 + e] = sv;
      }
    } else if (blk == 32 && tid < 32) {
      if (s > 0) {
        unsigned long long k = keys[tid];
        int n = (int)(0xFFFFFFFFu - (unsigned)(k & 0xFFFFFFFFull));
        tok[tid] = n;
        decoded[tid * 50 + s] = n;
      }
      keys[tid] = 0ULL;  // zero AFTER read, before this step's proj
    }
    GRID_BAR();

    // ---- phases B/B2: GRU layers (blocks 0..63) ----
    for (int layer = 0; layer < 2; ++layer) {
      if (blk < 64) {
        const float* A1   = layer ? (h0d + nxt * 16384) : emb;
        const int* tki    = layer ? (const int*)0 : tok;
        int len1          = 512;
        const float* A2   = layer ? (const float*)0 : ctxb;
        int len2          = layer ? 0 : 1024;
        const float* Wih  = layer ? dec_Wih1 : dec_Wih0;
        const float* bih  = layer ? dec_bih1 : dec_bih0;
        const float* Whh  = layer ? dec_Whh1 : dec_Whh0;
        const float* bhh  = layer ? dec_bhh1 : dec_bhh0;
        const float* h_in = layer ? (h1d + cur * 16384) : (h0d + cur * 16384);
        float* h_out      = layer ? (h1d + nxt * 16384) : (h0d + nxt * 16384);
        int b = bb31, j = (blk << 3) + jj;
        int Kin = len1 + len2;
        int K4 = Kin >> 2, len1_4 = len1 >> 2;
        int sw5 = b & 31;
        const float4* wir = (const float4*)(Wih + (size_t)j * Kin);
        const float4* wiz = (const float4*)(Wih + (size_t)(512 + j) * Kin);
        const float4* win = (const float4*)(Wih + (size_t)(1024 + j) * Kin);
        float gr = 0.f, gz = 0.f, gn = 0.f;
        for (int k0 = 0; k0 < K4; k0 += 32) {
          __syncthreads();
          for (int idx = tid; idx < 1024; idx += 256) {
            int bs = idx >> 5, kf = idx & 31;
            int gk = k0 + kf;
            float4 v;
            if (gk < len1_4) {
              const float* src = tki ? (A1 + (size_t)tki[bs] * len1) : (A1 + (size_t)bs * len1);
              v = ((const float4*)src)[gk];
            } else {
              v = ((const float4*)(A2 + (size_t)bs * len2))[gk - len1_4];
            }
            SB[(bs << 5) + (kf ^ (bs & 31))] = v;
          }
          __syncthreads();
          const float4* xrow = SB + (b << 5);
          const float4* wr_ = wir + k0;
          const float4* wz_ = wiz + k0;
          const float4* wn_ = win + k0;
#pragma unroll 4
          for (int kf = 0; kf < 32; ++kf) {
            float4 xv = xrow[kf ^ sw5];
            float4 r4 = wr_[kf];
            float4 z4 = wz_[kf];
            float4 n4 = wn_[kf];
            gr += xv.x * r4.x + xv.y * r4.y + xv.z * r4.z + xv.w * r4.w;
            gz += xv.x * z4.x + xv.y * z4.y + xv.z * z4.z + xv.w * z4.w;
            gn += xv.x * n4.x + xv.y * n4.y + xv.z * n4.z + xv.w * n4.w;
          }
        }
        const float4* whr = (const float4*)(Whh + (size_t)j * 512);
        const float4* whz = (const float4*)(Whh + (size_t)(512 + j) * 512);
        const float4* whn = (const float4*)(Whh + (size_t)(1024 + j) * 512);
        float sr = 0.f, sz = 0.f, sn = 0.f;
        for (int k0 = 0; k0 < 128; k0 += 32) {
          __syncthreads();
          for (int idx = tid; idx < 1024; idx += 256) {
            int bs = idx >> 5, kf = idx & 31;
            float4 v = ((const float4*)(h_in + (size_t)bs * 512))[k0 + kf];
            SB[(bs << 5) + (kf ^ (bs & 31))] = v;
          }
          __syncthreads();
          const float4* xrow = SB + (b << 5);
          const float4* wr_ = whr + k0;
          const float4* wz_ = whz + k0;
          const float4* wn_ = whn + k0;
#pragma unroll 4
          for (int kf = 0; kf < 32; ++kf) {
            float4 xv = xrow[kf ^ sw5];
            float4 r4 = wr_[kf];
            float4 z4 = wz_[kf];
            float4 n4 = wn_[kf];
            sr += xv.x * r4.x + xv.y * r4.y + xv.z * r4.z + xv.w * r4.w;
            sz += xv.x * z4.x + xv.y * z4.y + xv.z * z4.z + xv.w * z4.w;
            sn += xv.x * n4.x + xv.y * n4.y + xv.z * n4.z + xv.w * n4.w;
          }
        }
        float r = sigmoidf_(gr + bih[j] + sr + bhh[j]);
        float z = sigmoidf_(gz + bih[512 + j] + sz + bhh[512 + j]);
        float n = tanhf(gn + bih[1024 + j] + r * (sn + bhh[1024 + j]));
        float hj = h_in[b * 512 + j];
        h_out[b * 512 + j] = (1.f - z) * n + z * hj;
      }
      GRID_BAR();
    }

    // ---- phase C: proj + argmax (blocks 0..249), 96-float4 chunks for deep MLP ----
    if (blk < 250) {
      const float* h1n = h1d + nxt * 16384;
      int n = blk * 32 + nl;
      float acc[32];
#pragma unroll
      for (int b = 0; b < 32; ++b) acc[b] = 0.f;
      const float4* W4 = (const float4*)(proj_W + (size_t)n * 1536);
      for (int c = 0; c < 4; ++c) {
        __syncthreads();
#pragma unroll
        for (int r = 0; r < 12; ++r) {
          int e = r * 256 + tid;          // 0..3071
          int bb = e / 96;
          int kk = e - bb * 96;
          int gk = c * 96 + kk;
          float4 v;
          if (gk < 128) v = ((const float4*)(h1n + (size_t)bb * 512))[gk];
          else v = ((const float4*)(ctxb + (size_t)bb * 1024))[gk - 128];
          SB[bb * 96 + kk] = v;
        }
        __syncthreads();
        const float4* wp = W4 + c * 96;
#pragma unroll
        for (int j = 0; j < 12; ++j) {
          float4 wv = wp[j * 8 + s8];
          const float4* xp = SB + j * 8 + s8;
#pragma unroll
          for (int b = 0; b < 32; ++b) {
            float4 xv = xp[b * 96];
            acc[b] += wv.x * xv.x + wv.y * xv.y + wv.z * xv.z + wv.w * xv.w;
          }
        }
      }
#pragma unroll
      for (int b = 0; b < 32; ++b) {
        float v = acc[b];
        v += __shfl_xor(v, 1);
        v += __shfl_xor(v, 2);
        v += __shfl_xor(v, 4);
        acc[b] = v;
      }
      if (s8 == 0) {
        float bv = proj_b[n];
#pragma unroll
        for (int b = 0; b < 32; ++b) {
          float val = acc[b] + bv;
          unsigned u = __float_as_uint(val);
          u = (u & 0x80000000u) ? ~u : (u | 0x80000000u);
          ksh[nl * 33 + b] =
              ((unsigned long long)u << 32) | (unsigned long long)(0xFFFFFFFFu - (unsigned)n);
        }
      }
      __syncthreads();
      if (tid < 32) {
        unsigned long long best = 0ULL;
#pragma unroll 8
        for (int q = 0; q < 32; ++q) {
          unsigned long long v = ksh[q * 33 + tid];
          if (v > best) best = v;
        }
        atomicMax(&keys[tid], best);
      }
      __syncthreads();
    }
    GRID_BAR();
  }
  if (blk == 0 && tid < 32) {
    unsigned long long k = keys[tid];
    decoded[tid * 50 + 49] = (int)(0xFFFFFFFFu - (unsigned)(k & 0xFFFFFFFFull));
  }
}

__global__ void init_kernel(int* __restrict__ tok, int* __restrict__ decoded) {
  int b = threadIdx.x;
  if (b >= 32) return;
  tok[b] = 1;
  decoded[b * 50] = 1;
}

extern "C" void kernel_launch(void* const* d_in, const int* in_sizes, int n_in,
                              void* d_out, int out_size, void* d_ws, size_t ws_size,
                              hipStream_t stream) {
  const float* features  = (const float*)d_in[0];
  const float* conv_w1   = (const float*)d_in[1];
  const float* conv_b1   = (const float*)d_in[2];
  const float* conv_w2   = (const float*)d_in[3];
  const float* conv_b2   = (const float*)d_in[4];
  const float* enc_Wih_f = (const float*)d_in[5];
  const float* enc_Whh_f = (const float*)d_in[6];
  const float* enc_bih_f = (const float*)d_in[7];
  const float* enc_bhh_f = (const float*)d_in[8];
  const float* enc_Wih_b = (const float*)d_in[9];
  const float* enc_Whh_b = (const float*)d_in[10];
  const float* enc_bih_b = (const float*)d_in[11];
  const float* enc_bhh_b = (const float*)d_in[12];
  const float* bridge_W  = (const float*)d_in[13];
  const float* bridge_b  = (const float*)d_in[14];
  const float* emb       = (const float*)d_in[15];
  const float* attn_We   = (const float*)d_in[16];
  const float* attn_Wd   = (const float*)d_in[17];
  const float* attn_v    = (const float*)d_in[18];
  const float* dec_Wih0  = (const float*)d_in[19];
  const float* dec_Whh0  = (const float*)d_in[20];
  const float* dec_bih0  = (const float*)d_in[21];
  const float* dec_bhh0  = (const float*)d_in[22];
  const float* dec_Wih1  = (const float*)d_in[23];
  const float* dec_Whh1  = (const float*)d_in[24];
  const float* dec_bih1  = (const float*)d_in[25];
  const float* dec_bhh1  = (const float*)d_in[26];
  const float* proj_W    = (const float*)d_in[27];
  const float* proj_b    = (const float*)d_in[28];
  int* decoded = (int*)d_out;

  // ---- static workspace ----
  float* ws = nullptr;
  hipGetSymbolAddress((void**)&ws, HIP_SYMBOL(g_ws));
  float* P       = ws;                    // 10,485,760
  float* y1      = ws + 10485760;         //  4,194,304
  float* x2      = ws + 14680064;         //  2,097,152
  float* gi_f    = ws + 16777216;         //  6,291,456
  float* gi_b    = ws + 23068672;         //  6,291,456
  float* enc_out = ws + 29360128;         //  4,194,304
  float* enc_pj  = ws + 33554432;         //  2,097,152
  float* h_enc   = ws + 35651584;         //     65,536
  float* h0d     = ws + 35717120;         //     32,768
  float* h1d     = ws + 35749888;         //     32,768
  float* ctxb    = ws + 35782656;         //     32,768
  unsigned long long* keys = (unsigned long long*)(ws + 35815424);  // 32 u64
  int*   tok     = (int*)(ws + 35815488); //     32

  // ---- conv front-end ----
  im2col1_kernel<<<40960, 256, 0, stream>>>(features, P);
  sgemm128<<<dim3(4, 64), 256, 0, stream>>>(P, conv_w1, conv_b1, y1, 8192, 512, 1280, 1);
  im2col2_kernel<<<40960, 256, 0, stream>>>(y1, P);
  sgemm128<<<dim3(4, 32), 256, 0, stream>>>(P, conv_w2, conv_b2, x2, 4096, 512, 2560, 1);

  // ---- GRU input transforms ----
  sgemm128<<<dim3(12, 32), 256, 0, stream>>>(x2, enc_Wih_f, enc_bih_f, gi_f, 4096, 1536, 512, 0);
  sgemm128<<<dim3(12, 32), 256, 0, stream>>>(x2, enc_Wih_b, enc_bih_b, gi_b, 4096, 1536, 512, 0);

  // ---- persistent per-sequence encoder (XCD-aware dir mapping, no grid sync) ----
  enc_persist2<<<64, 1024, 0, stream>>>(gi_f, gi_b,
      enc_Whh_f, enc_bhh_f, enc_Whh_b, enc_bhh_b, h_enc, enc_out);

  // ---- bridge ----
  gemvB<<<32, 256, 0, stream>>>(h_enc, nullptr, 512, h_enc + 16384, 512,
      bridge_W, bridge_b, h0d, h1d, 512, 1024, 1024);

  // ---- enc_proj ----
  sgemm128<<<dim3(4, 32), 256, 0, stream>>>(enc_out, attn_We, nullptr, enc_pj, 4096, 512, 1024, 0);

  init_kernel<<<1, 64, 0, stream>>>(tok, decoded);
  reset_bar_kernel<<<1, 64, 0, stream>>>();

  // ---- persistent greedy attention decoder ----
  dec_persist<<<256, 256, 0, stream>>>(emb, attn_Wd, attn_v, enc_pj, enc_out,
      dec_Wih0, dec_bih0, dec_Whh0, dec_bhh0,
      dec_Wih1, dec_bih1, dec_Whh1, dec_bhh1,
      proj_W, proj_b, h0d, h1d, ctxb, keys, tok, decoded);
}

// Round 13
// 19471.234 us; speedup vs baseline: 1.3281x; 1.3281x over previous
//
#include <hip/hip_runtime.h>
#include <math.h>

#define DINLINE __device__ __forceinline__

DINLINE float sigmoidf_(float x) { return 1.f / (1.f + expf(-x)); }

// All scratch in static device memory — independent of ws_size (graph-safe, R3-R12 verified).
__device__ __align__(256) float g_ws[36200000];

// ---- grid-wide tree barrier state (decoder only). Reset before each dec_persist launch. ----
__device__ unsigned g_cnt;                          // level-2 arrival (16 group-lasts)
__device__ unsigned g_epoch;                        // global release flag
__device__ __align__(128) unsigned g_arr[16 * 32];  // per-group arrival counters, 128B apart
__device__ __align__(128) unsigned g_sub[16 * 32];  // per-group release flags, 128B apart

// Two-level ARRIVAL (16 parallel lines x 16 serial RMWs; R11's 256-serial-on-one-line was
// ~64us/barrier) + two-level WAIT (R11-proven). Device-scope atomics = cross-XCD coherent
// point; spin via atomic RMW-read (never a cacheable load).
#define GRID_BAR()                                                          \
  do {                                                                      \
    __syncthreads();                                                        \
    if (threadIdx.x == 0) {                                                 \
      __threadfence();                                                      \
      bar_target += 1u;                                                     \
      int grp_ = blockIdx.x >> 4;                                           \
      unsigned p_ = atomicAdd(&g_arr[grp_ * 32], 1u);                       \
      if (p_ == 15u) {                                                      \
        atomicExch(&g_arr[grp_ * 32], 0u);                                  \
        unsigned q_ = atomicAdd(&g_cnt, 1u);                                \
        if (q_ == 15u) {                                                    \
          atomicExch(&g_cnt, 0u);                                           \
          __threadfence();                                                  \
          atomicExch(&g_epoch, bar_target);                                 \
        }                                                                   \
      }                                                                     \
      if ((blockIdx.x & 15) == 0) {                                         \
        while (atomicAdd(&g_epoch, 0u) < bar_target)                        \
          __builtin_amdgcn_s_sleep(8);                                      \
        atomicExch(&g_sub[grp_ * 32], bar_target);                          \
      } else {                                                              \
        while (atomicAdd(&g_sub[grp_ * 32], 0u) < bar_target)               \
          __builtin_amdgcn_s_sleep(8);                                      \
      }                                                                     \
      __threadfence();                                                      \
    }                                                                       \
    __syncthreads();                                                        \
  } while (0)

__global__ void reset_bar_kernel() {
  int i = threadIdx.x;
  if (i == 0) { g_cnt = 0u; g_epoch = 0u; }
  if (i < 16) { g_arr[i * 32] = 0u; g_sub[i * 32] = 0u; }
}

// ---------------- im2col for the two convs ----------------
__global__ void im2col1_kernel(const float* __restrict__ feat, float* __restrict__ P) {
  size_t i = (size_t)blockIdx.x * 256 + threadIdx.x;
  int col = (int)(i % 1280);
  int row = (int)(i / 1280);
  int c = col / 5, k = col - c * 5;
  int l = row & 255, b = row >> 8;
  int pos = 2 * l + k - 2;
  P[i] = (pos >= 0 && pos < 512) ? feat[((size_t)b * 512 + pos) * 256 + c] : 0.f;
}

__global__ void im2col2_kernel(const float* __restrict__ y1, float* __restrict__ P) {
  size_t i = (size_t)blockIdx.x * 256 + threadIdx.x;
  int col = (int)(i % 2560);
  int row = (int)(i / 2560);
  int c = col / 5, k = col - c * 5;
  int l = row & 127, b = row >> 7;
  int pos = 2 * l + k - 2;
  P[i] = (pos >= 0 && pos < 256) ? y1[((size_t)b * 256 + pos) * 512 + c] : 0.f;
}

// ---------------- fp32 tiled GEMM (R4-verified) ----------------
__global__ __launch_bounds__(256) void sgemm128(
    const float* __restrict__ A, const float* __restrict__ B,
    const float* __restrict__ bias, float* __restrict__ C,
    int M, int N, int K, int relu) {
  __shared__ float As[8][132];
  __shared__ float Bs[8][132];
  int bm = blockIdx.y * 128, bn = blockIdx.x * 128;
  int tid = threadIdx.x;
  int tx = tid & 15, ty = tid >> 4;
  float acc[8][8];
#pragma unroll
  for (int i = 0; i < 8; ++i)
#pragma unroll
    for (int j = 0; j < 8; ++j) acc[i][j] = 0.f;
  int lr = tid >> 1;
  int lc = (tid & 1) * 4;
  const float* Arow = A + (size_t)(bm + lr) * K + lc;
  const float* Brow = B + (size_t)(bn + lr) * K + lc;
  for (int k0 = 0; k0 < K; k0 += 8) {
    float4 av = *(const float4*)(Arow + k0);
    float4 bv = *(const float4*)(Brow + k0);
    As[lc + 0][lr] = av.x; As[lc + 1][lr] = av.y; As[lc + 2][lr] = av.z; As[lc + 3][lr] = av.w;
    Bs[lc + 0][lr] = bv.x; Bs[lc + 1][lr] = bv.y; Bs[lc + 2][lr] = bv.z; Bs[lc + 3][lr] = bv.w;
    __syncthreads();
#pragma unroll
    for (int kk = 0; kk < 8; ++kk) {
      float4 a0 = *(const float4*)&As[kk][ty * 8];
      float4 a1 = *(const float4*)&As[kk][ty * 8 + 4];
      float4 b0 = *(const float4*)&Bs[kk][tx * 8];
      float4 b1 = *(const float4*)&Bs[kk][tx * 8 + 4];
      float aa[8] = {a0.x, a0.y, a0.z, a0.w, a1.x, a1.y, a1.z, a1.w};
      float bb[8] = {b0.x, b0.y, b0.z, b0.w, b1.x, b1.y, b1.z, b1.w};
#pragma unroll
      for (int i = 0; i < 8; ++i)
#pragma unroll
        for (int j = 0; j < 8; ++j) acc[i][j] += aa[i] * bb[j];
    }
    __syncthreads();
  }
#pragma unroll
  for (int i = 0; i < 8; ++i) {
    int m = bm + ty * 8 + i;
#pragma unroll
    for (int j = 0; j < 8; ++j) {
      int n = bn + tx * 8 + j;
      float v = acc[i][j] + (bias ? bias[n] : 0.f);
      if (relu) v = fmaxf(v, 0.f);
      C[(size_t)m * N + n] = v;
    }
  }
}

// ---------------- persistent per-(dir,b) encoder (R11-verified) ----------------
__global__ __launch_bounds__(1024) void enc_persist2(
    const float* __restrict__ gi_f, const float* __restrict__ gi_b,
    const float* __restrict__ Whh_f, const float* __restrict__ bhh_f,
    const float* __restrict__ Whh_b, const float* __restrict__ bhh_b,
    float* __restrict__ h_fin, float* __restrict__ enc_out) {
  __shared__ float hcur[512];
  __shared__ float gh[1536];
  int swz = blockIdx.x & 7;
  int dir = swz >> 2;
  int b = ((blockIdx.x >> 3) << 2) | (swz & 3);
  int tid = threadIdx.x;
  int sl = tid & 7, nl = tid >> 3;
  const float* gi  = dir ? gi_b  : gi_f;
  const float* Whh = dir ? Whh_b : Whh_f;
  const float* bhh = dir ? bhh_b : bhh_f;
  float bhr = 0.f, bhz = 0.f, bhn = 0.f;
  if (tid < 512) {
    hcur[tid] = 0.f;
    bhr = bhh[tid]; bhz = bhh[512 + tid]; bhn = bhh[1024 + tid];
  }
  __syncthreads();
  for (int s = 0; s < 128; ++s) {
    int t = dir ? (127 - s) : s;
#pragma unroll 2
    for (int pass = 0; pass < 12; ++pass) {
      int m = pass * 128 + nl;
      const float4* wp = (const float4*)(Whh + (size_t)m * 512);
      float a = 0.f;
#pragma unroll
      for (int q = 0; q < 16; ++q) {
        float4 wv = wp[q * 8 + sl];
        float4 hv = *(const float4*)&hcur[(q * 8 + sl) * 4];
        a += wv.x * hv.x + wv.y * hv.y + wv.z * hv.z + wv.w * hv.w;
      }
      a += __shfl_xor(a, 1);
      a += __shfl_xor(a, 2);
      a += __shfl_xor(a, 4);
      if (sl == 0) gh[m] = a;
    }
    __syncthreads();
    if (tid < 512) {
      int j = tid;
      const float* g = gi + ((size_t)b * 128 + t) * 1536;
      float r = sigmoidf_(g[j] + gh[j] + bhr);
      float z = sigmoidf_(g[512 + j] + gh[512 + j] + bhz);
      float n = tanhf(g[1024 + j] + r * (gh[1024 + j] + bhn));
      float hnew = (1.f - z) * n + z * hcur[j];
      hcur[j] = hnew;
      enc_out[((size_t)b * 128 + t) * 1024 + dir * 512 + j] = hnew;
    }
    __syncthreads();
  }
  if (tid < 512) h_fin[dir * 16384 + b * 512 + tid] = hcur[tid];
}

// ---------------- batch-shared GEMV (bridge only; R5-verified) ----------------
__global__ __launch_bounds__(256) void gemvB(
    const float* __restrict__ A1, const int* __restrict__ tokidx, int len1,
    const float* __restrict__ A2, int len2,
    const float* __restrict__ W, const float* __restrict__ bias,
    float* __restrict__ out0, float* __restrict__ out1, int split, int N, int K) {
  int tid = threadIdx.x;
  int s = tid & 7, nl = tid >> 3;
  int n = blockIdx.x * 32 + nl;
  __shared__ float4 xs4[32 * 32];
  float acc[32];
#pragma unroll
  for (int b = 0; b < 32; ++b) acc[b] = 0.f;
  const float4* W4 = (const float4*)(W + (size_t)n * K);
  int K4 = K >> 2;
  int len1_4 = len1 >> 2;
  for (int k0 = 0; k0 < K4; k0 += 32) {
    __syncthreads();
    for (int idx = tid; idx < 1024; idx += 256) {
      int b = idx >> 5, kf = idx & 31;
      int gk = k0 + kf;
      float4 v;
      if (gk < len1_4) {
        const float* src = tokidx ? (A1 + (size_t)tokidx[b] * len1) : (A1 + (size_t)b * len1);
        v = ((const float4*)src)[gk];
      } else {
        v = ((const float4*)(A2 + (size_t)b * len2))[gk - len1_4];
      }
      xs4[idx] = v;
    }
    __syncthreads();
    const float4* wp = W4 + k0;
#pragma unroll
    for (int j = 0; j < 4; ++j) {
      float4 wv = wp[j * 8 + s];
      const float4* xp = xs4 + j * 8 + s;
#pragma unroll
      for (int b = 0; b < 32; ++b) {
        float4 xv = xp[b * 32];
        acc[b] += wv.x * xv.x + wv.y * xv.y + wv.z * xv.z + wv.w * xv.w;
      }
    }
  }
#pragma unroll
  for (int b = 0; b < 32; ++b) {
    float v = acc[b];
    v += __shfl_xor(v, 1);
    v += __shfl_xor(v, 2);
    v += __shfl_xor(v, 4);
    acc[b] = v;
  }
  if (s == 0) {
    float bv = bias ? bias[n] : 0.f;
#pragma unroll
    for (int b = 0; b < 32; ++b) {
      float val = acc[b] + bv;
      if (n < split) out0[(size_t)b * split + n] = val;
      else out1[(size_t)b * (N - split) + (n - split)] = val;
    }
  }
}

// ---------------- persistent decoder: 49 steps x 4 phases ----------------
// SB 16KB (R11-proven chunk size; R12's 48KB/12-unroll spilled at VGPR cap).
__global__ __launch_bounds__(256) void dec_persist(
    const float* __restrict__ emb, const float* __restrict__ attn_Wd,
    const float* __restrict__ attn_v,
    const float* __restrict__ enc_pj, const float* __restrict__ enc_out,
    const float* __restrict__ dec_Wih0, const float* __restrict__ dec_bih0,
    const float* __restrict__ dec_Whh0, const float* __restrict__ dec_bhh0,
    const float* __restrict__ dec_Wih1, const float* __restrict__ dec_bih1,
    const float* __restrict__ dec_Whh1, const float* __restrict__ dec_bhh1,
    const float* __restrict__ proj_W, const float* __restrict__ proj_b,
    float* __restrict__ h0d, float* __restrict__ h1d,
    float* __restrict__ ctxb,
    unsigned long long* __restrict__ keys, int* __restrict__ tok,
    int* __restrict__ decoded) {
  __shared__ float4 SB[1024];                    // 16KB chunk staging
  __shared__ unsigned long long ksh[32 * 33];    // 8.4KB
  __shared__ float d_s[512];
  __shared__ float hb_s[512];
  __shared__ float red_s[256];
  __shared__ float sc_s[128];
  unsigned bar_target = 0u;
  int blk = blockIdx.x, tid = threadIdx.x;
  int s8 = tid & 7, nl = tid >> 3;               // gemv roles
  int bb31 = tid & 31, jj = tid >> 5;            // gru roles

  for (int s = 0; s < 49; ++s) {
    int cur = s & 1, nxt = (s + 1) & 1;
    const float* h1cur = h1d + cur * 16384;

    // ---- phase A: full attention per-b (dW inline from L2); blk32 decode+zero keys ----
    if (blk < 32) {
      int b = blk;
      hb_s[tid] = h1cur[b * 512 + tid];
      hb_s[tid + 256] = h1cur[b * 512 + 256 + tid];
      __syncthreads();
      for (int pass = 0; pass < 16; ++pass) {
        int a = pass * 32 + nl;
        const float4* wp = (const float4*)(attn_Wd + (size_t)a * 512);
        float sum = 0.f;
#pragma unroll
        for (int q = 0; q < 16; ++q) {
          float4 wv = wp[q * 8 + s8];
          float4 hv = *(const float4*)&hb_s[(q * 8 + s8) * 4];
          sum += wv.x * hv.x + wv.y * hv.y + wv.z * hv.z + wv.w * hv.w;
        }
        sum += __shfl_xor(sum, 1);
        sum += __shfl_xor(sum, 2);
        sum += __shfl_xor(sum, 4);
        if (s8 == 0) d_s[a] = sum;
      }
      __syncthreads();
      {
        int t = tid >> 1, part = tid & 1;
        const float* ep = enc_pj + ((size_t)b * 128 + t) * 512 + part * 256;
        const float* dd = d_s + part * 256;
        const float* vv = attn_v + part * 256;
        float sv = 0.f;
        for (int a = 0; a < 256; ++a) sv += tanhf(ep[a] + dd[a]) * vv[a];
        red_s[tid] = sv;
      }
      __syncthreads();
      if (tid < 128) sc_s[tid] = red_s[tid * 2] + red_s[tid * 2 + 1];
      __syncthreads();
      if (tid == 0) {
        float m = -1e30f;
        for (int t = 0; t < 128; ++t) m = fmaxf(m, sc_s[t]);
        float sum = 0.f;
        for (int t = 0; t < 128; ++t) { float e = expf(sc_s[t] - m); sc_s[t] = e; sum += e; }
        float inv = 1.f / sum;
        for (int t = 0; t < 128; ++t) sc_s[t] *= inv;
      }
      __syncthreads();
      for (int e = tid; e < 1024; e += 256) {
        const float* eo = enc_out + (size_t)b * 131072 + e;
        float sv = 0.f;
        for (int t = 0; t < 128; ++t) sv += sc_s[t] * eo[(size_t)t * 1024];
        ctxb[b * 1024 + e] = sv;
      }
    } else if (blk == 32 && tid < 32) {
      if (s > 0) {
        unsigned long long k = keys[tid];
        int n = (int)(0xFFFFFFFFu - (unsigned)(k & 0xFFFFFFFFull));
        tok[tid] = n;
        decoded[tid * 50 + s] = n;
      }
      keys[tid] = 0ULL;  // zero AFTER read, before this step's proj
    }
    GRID_BAR();

    // ---- phases B/B2: GRU layers (blocks 0..63) ----
    for (int layer = 0; layer < 2; ++layer) {
      if (blk < 64) {
        const float* A1   = layer ? (h0d + nxt * 16384) : emb;
        const int* tki    = layer ? (const int*)0 : tok;
        int len1          = 512;
        const float* A2   = layer ? (const float*)0 : ctxb;
        int len2          = layer ? 0 : 1024;
        const float* Wih  = layer ? dec_Wih1 : dec_Wih0;
        const float* bih  = layer ? dec_bih1 : dec_bih0;
        const float* Whh  = layer ? dec_Whh1 : dec_Whh0;
        const float* bhh  = layer ? dec_bhh1 : dec_bhh0;
        const float* h_in = layer ? (h1d + cur * 16384) : (h0d + cur * 16384);
        float* h_out      = layer ? (h1d + nxt * 16384) : (h0d + nxt * 16384);
        int b = bb31, j = (blk << 3) + jj;
        int Kin = len1 + len2;
        int K4 = Kin >> 2, len1_4 = len1 >> 2;
        int sw5 = b & 31;
        const float4* wir = (const float4*)(Wih + (size_t)j * Kin);
        const float4* wiz = (const float4*)(Wih + (size_t)(512 + j) * Kin);
        const float4* win = (const float4*)(Wih + (size_t)(1024 + j) * Kin);
        float gr = 0.f, gz = 0.f, gn = 0.f;
        for (int k0 = 0; k0 < K4; k0 += 32) {
          __syncthreads();
          for (int idx = tid; idx < 1024; idx += 256) {
            int bs = idx >> 5, kf = idx & 31;
            int gk = k0 + kf;
            float4 v;
            if (gk < len1_4) {
              const float* src = tki ? (A1 + (size_t)tki[bs] * len1) : (A1 + (size_t)bs * len1);
              v = ((const float4*)src)[gk];
            } else {
              v = ((const float4*)(A2 + (size_t)bs * len2))[gk - len1_4];
            }
            SB[(bs << 5) + (kf ^ (bs & 31))] = v;
          }
          __syncthreads();
          const float4* xrow = SB + (b << 5);
          const float4* wr_ = wir + k0;
          const float4* wz_ = wiz + k0;
          const float4* wn_ = win + k0;
#pragma unroll 4
          for (int kf = 0; kf < 32; ++kf) {
            float4 xv = xrow[kf ^ sw5];
            float4 r4 = wr_[kf];
            float4 z4 = wz_[kf];
            float4 n4 = wn_[kf];
            gr += xv.x * r4.x + xv.y * r4.y + xv.z * r4.z + xv.w * r4.w;
            gz += xv.x * z4.x + xv.y * z4.y + xv.z * z4.z + xv.w * z4.w;
            gn += xv.x * n4.x + xv.y * n4.y + xv.z * n4.z + xv.w * n4.w;
          }
        }
        const float4* whr = (const float4*)(Whh + (size_t)j * 512);
        const float4* whz = (const float4*)(Whh + (size_t)(512 + j) * 512);
        const float4* whn = (const float4*)(Whh + (size_t)(1024 + j) * 512);
        float sr = 0.f, sz = 0.f, sn = 0.f;
        for (int k0 = 0; k0 < 128; k0 += 32) {
          __syncthreads();
          for (int idx = tid; idx < 1024; idx += 256) {
            int bs = idx >> 5, kf = idx & 31;
            float4 v = ((const float4*)(h_in + (size_t)bs * 512))[k0 + kf];
            SB[(bs << 5) + (kf ^ (bs & 31))] = v;
          }
          __syncthreads();
          const float4* xrow = SB + (b << 5);
          const float4* wr_ = whr + k0;
          const float4* wz_ = whz + k0;
          const float4* wn_ = whn + k0;
#pragma unroll 4
          for (int kf = 0; kf < 32; ++kf) {
            float4 xv = xrow[kf ^ sw5];
            float4 r4 = wr_[kf];
            float4 z4 = wz_[kf];
            float4 n4 = wn_[kf];
            sr += xv.x * r4.x + xv.y * r4.y + xv.z * r4.z + xv.w * r4.w;
            sz += xv.x * z4.x + xv.y * z4.y + xv.z * z4.z + xv.w * z4.w;
            sn += xv.x * n4.x + xv.y * n4.y + xv.z * n4.z + xv.w * n4.w;
          }
        }
        float r = sigmoidf_(gr + bih[j] + sr + bhh[j]);
        float z = sigmoidf_(gz + bih[512 + j] + sz + bhh[512 + j]);
        float n = tanhf(gn + bih[1024 + j] + r * (sn + bhh[1024 + j]));
        float hj = h_in[b * 512 + j];
        h_out[b * 512 + j] = (1.f - z) * n + z * hj;
      }
      GRID_BAR();
    }

    // ---- phase C: proj + argmax (blocks 0..249), R11-proven inner shape ----
    if (blk < 250) {
      const float* h1n = h1d + nxt * 16384;
      int n = blk * 32 + nl;
      float acc[32];
#pragma unroll
      for (int b = 0; b < 32; ++b) acc[b] = 0.f;
      const float4* W4 = (const float4*)(proj_W + (size_t)n * 1536);
      for (int k0 = 0; k0 < 384; k0 += 32) {
        __syncthreads();
        for (int idx = tid; idx < 1024; idx += 256) {
          int b = idx >> 5, kf = idx & 31;
          int gk = k0 + kf;
          float4 v;
          if (gk < 128) v = ((const float4*)(h1n + (size_t)b * 512))[gk];
          else v = ((const float4*)(ctxb + (size_t)b * 1024))[gk - 128];
          SB[idx] = v;
        }
        __syncthreads();
        const float4* wp = W4 + k0;
#pragma unroll
        for (int j = 0; j < 4; ++j) {
          float4 wv = wp[j * 8 + s8];
          const float4* xp = SB + j * 8 + s8;
#pragma unroll
          for (int b = 0; b < 32; ++b) {
            float4 xv = xp[b * 32];
            acc[b] += wv.x * xv.x + wv.y * xv.y + wv.z * xv.z + wv.w * xv.w;
          }
        }
      }
#pragma unroll
      for (int b = 0; b < 32; ++b) {
        float v = acc[b];
        v += __shfl_xor(v, 1);
        v += __shfl_xor(v, 2);
        v += __shfl_xor(v, 4);
        acc[b] = v;
      }
      if (s8 == 0) {
        float bv = proj_b[n];
#pragma unroll
        for (int b = 0; b < 32; ++b) {
          float val = acc[b] + bv;
          unsigned u = __float_as_uint(val);
          u = (u & 0x80000000u) ? ~u : (u | 0x80000000u);
          ksh[nl * 33 + b] =
              ((unsigned long long)u << 32) | (unsigned long long)(0xFFFFFFFFu - (unsigned)n);
        }
      }
      __syncthreads();
      if (tid < 32) {
        unsigned long long best = 0ULL;
#pragma unroll 8
        for (int q = 0; q < 32; ++q) {
          unsigned long long v = ksh[q * 33 + tid];
          if (v > best) best = v;
        }
        atomicMax(&keys[tid], best);
      }
      __syncthreads();
    }
    GRID_BAR();
  }
  if (blk == 0 && tid < 32) {
    unsigned long long k = keys[tid];
    decoded[tid * 50 + 49] = (int)(0xFFFFFFFFu - (unsigned)(k & 0xFFFFFFFFull));
  }
}

__global__ void init_kernel(int* __restrict__ tok, int* __restrict__ decoded) {
  int b = threadIdx.x;
  if (b >= 32) return;
  tok[b] = 1;
  decoded[b * 50] = 1;
}

extern "C" void kernel_launch(void* const* d_in, const int* in_sizes, int n_in,
                              void* d_out, int out_size, void* d_ws, size_t ws_size,
                              hipStream_t stream) {
  const float* features  = (const float*)d_in[0];
  const float* conv_w1   = (const float*)d_in[1];
  const float* conv_b1   = (const float*)d_in[2];
  const float* conv_w2   = (const float*)d_in[3];
  const float* conv_b2   = (const float*)d_in[4];
  const float* enc_Wih_f = (const float*)d_in[5];
  const float* enc_Whh_f = (const float*)d_in[6];
  const float* enc_bih_f = (const float*)d_in[7];
  const float* enc_bhh_f = (const float*)d_in[8];
  const float* enc_Wih_b = (const float*)d_in[9];
  const float* enc_Whh_b = (const float*)d_in[10];
  const float* enc_bih_b = (const float*)d_in[11];
  const float* enc_bhh_b = (const float*)d_in[12];
  const float* bridge_W  = (const float*)d_in[13];
  const float* bridge_b  = (const float*)d_in[14];
  const float* emb       = (const float*)d_in[15];
  const float* attn_We   = (const float*)d_in[16];
  const float* attn_Wd   = (const float*)d_in[17];
  const float* attn_v    = (const float*)d_in[18];
  const float* dec_Wih0  = (const float*)d_in[19];
  const float* dec_Whh0  = (const float*)d_in[20];
  const float* dec_bih0  = (const float*)d_in[21];
  const float* dec_bhh0  = (const float*)d_in[22];
  const float* dec_Wih1  = (const float*)d_in[23];
  const float* dec_Whh1  = (const float*)d_in[24];
  const float* dec_bih1  = (const float*)d_in[25];
  const float* dec_bhh1  = (const float*)d_in[26];
  const float* proj_W    = (const float*)d_in[27];
  const float* proj_b    = (const float*)d_in[28];
  int* decoded = (int*)d_out;

  // ---- static workspace ----
  float* ws = nullptr;
  hipGetSymbolAddress((void**)&ws, HIP_SYMBOL(g_ws));
  float* P       = ws;                    // 10,485,760
  float* y1      = ws + 10485760;         //  4,194,304
  float* x2      = ws + 14680064;         //  2,097,152
  float* gi_f    = ws + 16777216;         //  6,291,456
  float* gi_b    = ws + 23068672;         //  6,291,456
  float* enc_out = ws + 29360128;         //  4,194,304
  float* enc_pj  = ws + 33554432;         //  2,097,152
  float* h_enc   = ws + 35651584;         //     65,536
  float* h0d     = ws + 35717120;         //     32,768
  float* h1d     = ws + 35749888;         //     32,768
  float* ctxb    = ws + 35782656;         //     32,768
  unsigned long long* keys = (unsigned long long*)(ws + 35815424);  // 32 u64
  int*   tok     = (int*)(ws + 35815488); //     32

  // ---- conv front-end ----
  im2col1_kernel<<<40960, 256, 0, stream>>>(features, P);
  sgemm128<<<dim3(4, 64), 256, 0, stream>>>(P, conv_w1, conv_b1, y1, 8192, 512, 1280, 1);
  im2col2_kernel<<<40960, 256, 0, stream>>>(y1, P);
  sgemm128<<<dim3(4, 32), 256, 0, stream>>>(P, conv_w2, conv_b2, x2, 4096, 512, 2560, 1);

  // ---- GRU input transforms ----
  sgemm128<<<dim3(12, 32), 256, 0, stream>>>(x2, enc_Wih_f, enc_bih_f, gi_f, 4096, 1536, 512, 0);
  sgemm128<<<dim3(12, 32), 256, 0, stream>>>(x2, enc_Wih_b, enc_bih_b, gi_b, 4096, 1536, 512, 0);

  // ---- persistent per-sequence encoder (XCD-aware dir mapping, no grid sync) ----
  enc_persist2<<<64, 1024, 0, stream>>>(gi_f, gi_b,
      enc_Whh_f, enc_bhh_f, enc_Whh_b, enc_bhh_b, h_enc, enc_out);

  // ---- bridge ----
  gemvB<<<32, 256, 0, stream>>>(h_enc, nullptr, 512, h_enc + 16384, 512,
      bridge_W, bridge_b, h0d, h1d, 512, 1024, 1024);

  // ---- enc_proj ----
  sgemm128<<<dim3(4, 32), 256, 0, stream>>>(enc_out, attn_We, nullptr, enc_pj, 4096, 512, 1024, 0);

  init_kernel<<<1, 64, 0, stream>>>(tok, decoded);
  reset_bar_kernel<<<1, 64, 0, stream>>>();

  // ---- persistent greedy attention decoder ----
  dec_persist<<<256, 256, 0, stream>>>(emb, attn_Wd, attn_v, enc_pj, enc_out,
      dec_Wih0, dec_bih0, dec_Whh0, dec_bhh0,
      dec_Wih1, dec_bih1, dec_Whh1, dec_bhh1,
      proj_W, proj_b, h0d, h1d, ctxb, keys, tok, decoded);
}